// Round 1
// baseline (1430.452 us; speedup 1.0000x reference)
//
#include <hip/hip_runtime.h>

namespace {
constexpr int kB = 64;
constexpr int kN = 8400;
constexpr int kReg = 64;
constexpr int kCls = 80;
constexpr int kStride = kReg + kCls; // 144
constexpr int kMaxOut = 100;
constexpr float kScoreTh = 0.3f;
constexpr float kIouTh = 0.5f;
constexpr float kNegInf = -1e30f;
}

// ---------------------------------------------------------------------------
// Stage 1: DFL decode + class max/argmax. One thread per (b, n) anchor.
// ---------------------------------------------------------------------------
__global__ __launch_bounds__(256) void decode_k(
    const float* __restrict__ preds,
    const float* __restrict__ anchors,
    float4* __restrict__ boxes,
    float* __restrict__ scores,
    int* __restrict__ labels)
{
    int idx = blockIdx.x * blockDim.x + threadIdx.x;
    if (idx >= kB * kN) return;
    int n = idx - (idx / kN) * kN;
    const float* p = preds + (size_t)idx * kStride;

    // DFL: 4 sides x 16 bins, softmax-expectation per side.
    float d[4];
#pragma unroll
    for (int s = 0; s < 4; ++s) {
        float x[16];
        const float4* q = (const float4*)(p + s * 16);
#pragma unroll
        for (int j = 0; j < 4; ++j) ((float4*)x)[j] = q[j];
        float m = x[0];
#pragma unroll
        for (int j = 1; j < 16; ++j) m = fmaxf(m, x[j]);
        float se = 0.f, we = 0.f;
#pragma unroll
        for (int j = 0; j < 16; ++j) {
            float t = expf(x[j] - m);
            se += t;
            we += t * (float)j;
        }
        d[s] = we / se;
    }

    float4 a = ((const float4*)anchors)[n];
    float ah0 = a.z - a.x, ah1 = a.w - a.y;
    float c0 = (a.x + a.z) * 0.5f, c1 = (a.y + a.w) * 0.5f;
    // bc = (br - tl) * 0.5 * anchors_hw + ctr ; bhw = (br + tl) * anchors_hw
    float bc0 = (d[2] - d[0]) * 0.5f * ah0 + c0;
    float bc1 = (d[3] - d[1]) * 0.5f * ah1 + c1;
    float bh0 = (d[2] + d[0]) * ah0;
    float bh1 = (d[3] + d[1]) * ah1;
    boxes[idx] = make_float4(bc0 - bh0 * 0.5f, bc1 - bh1 * 0.5f,
                             bc0 + bh0 * 0.5f, bc1 + bh1 * 0.5f);

    // Class max + argmax (first-occurrence on ties, strict >).
    const float4* cl = (const float4*)(p + kReg);
    float best = -3e38f; int bl = 0;
#pragma unroll
    for (int c = 0; c < kCls / 4; ++c) {
        float4 v = cl[c];
        if (v.x > best) { best = v.x; bl = 4 * c + 0; }
        if (v.y > best) { best = v.y; bl = 4 * c + 1; }
        if (v.z > best) { best = v.z; bl = 4 * c + 2; }
        if (v.w > best) { best = v.w; bl = 4 * c + 3; }
    }
    scores[idx] = best;
    labels[idx] = bl;
}

// ---------------------------------------------------------------------------
// Stage 2: greedy NMS, one block per image. Scores in LDS; boxes from global
// (L2-resident). 100 serial iterations of argmax + IoU suppression.
// ---------------------------------------------------------------------------
__global__ __launch_bounds__(256) void nms_k(
    const float4* __restrict__ boxes,
    const float* __restrict__ scores,
    const int* __restrict__ labels,
    float* __restrict__ out)
{
    __shared__ float ssc[kN];
    __shared__ float rv[256];
    __shared__ int   ri[256];
    __shared__ int   sel[kMaxOut];

    const int b = blockIdx.x;
    const int tid = threadIdx.x;
    const float* sc = scores + (size_t)b * kN;
    const float4* bx = boxes + (size_t)b * kN;

    for (int i = tid; i < kN; i += 256) {
        float s = sc[i];
        ssc[i] = (s > kScoreTh) ? s : kNegInf;
    }
    __syncthreads();

    for (int it = 0; it < kMaxOut; ++it) {
        // ---- block-wide argmax (first-occurrence tie-break) ----
        float bv = -3e38f; int bi = 0x7fffffff;
        for (int i = tid; i < kN; i += 256) {
            float v = ssc[i];
            if (v > bv) { bv = v; bi = i; }   // strict >: keeps smallest i per thread
        }
        rv[tid] = bv; ri[tid] = bi;
        __syncthreads();
        for (int s = 128; s > 0; s >>= 1) {
            if (tid < s) {
                float v2 = rv[tid + s]; int i2 = ri[tid + s];
                float v1 = rv[tid];     int i1 = ri[tid];
                if (v2 > v1 || (v2 == v1 && i2 < i1)) { rv[tid] = v2; ri[tid] = i2; }
            }
            __syncthreads();
        }
        int j = ri[0];
        float vj = rv[0];
        bool valid = vj > 0.5f * kNegInf;   // sc[j] > NEG_INF * 0.5
        if (tid == 0) sel[it] = valid ? j : -1;

        // ---- IoU suppression (runs even when invalid: matches ref scan) ----
        float4 bj = bx[j];
        float a1 = (bj.z - bj.x) * (bj.w - bj.y);
        for (int i = tid; i < kN; i += 256) {
            float s = ssc[i];
            if (s > 0.5f * kNegInf) {   // already-dead entries can't change
                float4 bi4 = bx[i];
                float t0 = fmaxf(bj.x, bi4.x);
                float t1 = fmaxf(bj.y, bi4.y);
                float b0 = fminf(bj.z, bi4.z);
                float b1 = fminf(bj.w, bi4.w);
                float inter = fmaxf(b0 - t0, 0.f) * fmaxf(b1 - t1, 0.f);
                float a2 = (bi4.z - bi4.x) * (bi4.w - bi4.y);
                float iou = inter / (a1 + a2 - inter + 1e-9f);
                if (iou > kIouTh || i == j) ssc[i] = kNegInf;
            }
        }
        __syncthreads();
    }

    // ---- epilogue: gather selections ----
    if (tid < kMaxOut) {
        int idx = sel[tid];
        bool valid = idx >= 0;
        int safe = valid ? idx : 0;
        float4 bxv = bx[safe];
        float v = valid ? 1.f : 0.f;
        ((float4*)out)[b * kMaxOut + tid] =
            make_float4(bxv.x * v, bxv.y * v, bxv.z * v, bxv.w * v);
        out[kB * kMaxOut * 4 + b * kMaxOut + tid] =
            valid ? (float)labels[(size_t)b * kN + safe] : -1.0f;
        out[kB * kMaxOut * 5 + b * kMaxOut + tid] =
            valid ? sc[safe] : 0.0f;
    }
}

extern "C" void kernel_launch(void* const* d_in, const int* in_sizes, int n_in,
                              void* d_out, int out_size, void* d_ws, size_t ws_size,
                              hipStream_t stream)
{
    const float* preds = (const float*)d_in[0];
    const float* anchors = (const float*)d_in[1];
    float* out = (float*)d_out;

    char* ws = (char*)d_ws;
    float4* boxes = (float4*)ws;                               // 64*8400*16 B = 8.6 MB
    float* scores = (float*)(ws + (size_t)kB * kN * 16);       // 2.15 MB
    int* labels = (int*)(ws + (size_t)kB * kN * 20);           // 2.15 MB

    int total = kB * kN;
    decode_k<<<(total + 255) / 256, 256, 0, stream>>>(preds, anchors, boxes, scores, labels);
    nms_k<<<kB, 256, 0, stream>>>(boxes, scores, labels, out);
}

// Round 2
// 608.758 us; speedup vs baseline: 2.3498x; 2.3498x over previous
//
#include <hip/hip_runtime.h>

namespace {
constexpr int kB = 64;
constexpr int kN = 8400;
constexpr int kNP = 16384;          // padded pow2 per image for bitonic
constexpr int kReg = 64;
constexpr int kCls = 80;
constexpr int kStride = kReg + kCls; // 144
constexpr int kMaxOut = 100;
constexpr float kScoreTh = 0.3f;
constexpr float kIouTh = 0.5f;
}

// ---------------------------------------------------------------------------
// Stage 1: DFL decode + class max/argmax. One thread per (b, n) anchor.
// (unchanged from round 1 — verified absmax 0.0)
// ---------------------------------------------------------------------------
__global__ __launch_bounds__(256) void decode_k(
    const float* __restrict__ preds,
    const float* __restrict__ anchors,
    float4* __restrict__ boxes,
    float* __restrict__ scores,
    int* __restrict__ labels)
{
    int idx = blockIdx.x * blockDim.x + threadIdx.x;
    if (idx >= kB * kN) return;
    int n = idx - (idx / kN) * kN;
    const float* p = preds + (size_t)idx * kStride;

    float d[4];
#pragma unroll
    for (int s = 0; s < 4; ++s) {
        float x[16];
        const float4* q = (const float4*)(p + s * 16);
#pragma unroll
        for (int j = 0; j < 4; ++j) ((float4*)x)[j] = q[j];
        float m = x[0];
#pragma unroll
        for (int j = 1; j < 16; ++j) m = fmaxf(m, x[j]);
        float se = 0.f, we = 0.f;
#pragma unroll
        for (int j = 0; j < 16; ++j) {
            float t = expf(x[j] - m);
            se += t;
            we += t * (float)j;
        }
        d[s] = we / se;
    }

    float4 a = ((const float4*)anchors)[n];
    float ah0 = a.z - a.x, ah1 = a.w - a.y;
    float c0 = (a.x + a.z) * 0.5f, c1 = (a.y + a.w) * 0.5f;
    float bc0 = (d[2] - d[0]) * 0.5f * ah0 + c0;
    float bc1 = (d[3] - d[1]) * 0.5f * ah1 + c1;
    float bh0 = (d[2] + d[0]) * ah0;
    float bh1 = (d[3] + d[1]) * ah1;
    boxes[idx] = make_float4(bc0 - bh0 * 0.5f, bc1 - bh1 * 0.5f,
                             bc0 + bh0 * 0.5f, bc1 + bh1 * 0.5f);

    const float4* cl = (const float4*)(p + kReg);
    float best = -3e38f; int bl = 0;
#pragma unroll
    for (int c = 0; c < kCls / 4; ++c) {
        float4 v = cl[c];
        if (v.x > best) { best = v.x; bl = 4 * c + 0; }
        if (v.y > best) { best = v.y; bl = 4 * c + 1; }
        if (v.z > best) { best = v.z; bl = 4 * c + 2; }
        if (v.w > best) { best = v.w; bl = 4 * c + 3; }
    }
    scores[idx] = best;
    labels[idx] = bl;
}

// ---------------------------------------------------------------------------
// Sort stage A: build 64-bit keys. Ascending key order == (score desc, idx asc).
// key = (~orderable(scorebits) << 32) | idx ; invalid/pad = all-ones.
// ---------------------------------------------------------------------------
__global__ __launch_bounds__(256) void keys_k(
    const float* __restrict__ scores, unsigned long long* __restrict__ keys)
{
    int t = blockIdx.x * 256 + threadIdx.x;      // over kB*kNP
    int b = t >> 14, i = t & (kNP - 1);
    unsigned long long k = ~0ULL;
    if (i < kN) {
        float s = scores[b * kN + i];
        if (s > kScoreTh) {
            unsigned u = __float_as_uint(s);
            unsigned o = u ^ ((u & 0x80000000u) ? 0xFFFFFFFFu : 0x80000000u);
            k = ((unsigned long long)(~o) << 32) | (unsigned)i;
        }
    }
    keys[t] = k;
}

// ---------------------------------------------------------------------------
// Sort stage B: bitonic stages size=2..8192 within each 8192-element half.
// Half h=0 sorted ascending, h=1 descending -> 16384 bitonic sequence.
// ---------------------------------------------------------------------------
__global__ __launch_bounds__(512) void sortB_k(unsigned long long* __restrict__ keys)
{
    __shared__ unsigned long long lk[8192];      // 64 KB
    const int h = blockIdx.x & 1;
    unsigned long long* base = keys + ((size_t)blockIdx.x << 13);
    for (int t = threadIdx.x; t < 8192; t += 512) lk[t] = base[t];
    __syncthreads();
    for (int size = 2; size <= 8192; size <<= 1) {
        const bool isTop = (size == 8192);
        for (int stride = size >> 1; stride > 0; stride >>= 1) {
#pragma unroll
            for (int p = 0; p < 8; ++p) {
                int n = threadIdx.x + (p << 9);
                int i = ((n & ~(stride - 1)) << 1) | (n & (stride - 1));
                int j = i + stride;
                bool desc = isTop ? (h == 1) : ((i & size) != 0);
                unsigned long long a = lk[i], c = lk[j];
                bool sw = desc ? (c > a) : (a > c);
                if (sw) { lk[i] = c; lk[j] = a; }
            }
            __syncthreads();
        }
    }
    for (int t = threadIdx.x; t < 8192; t += 512) base[t] = lk[t];
}

// ---------------------------------------------------------------------------
// Sort stage C: the single stride-8192 global pass of the final merge stage.
// ---------------------------------------------------------------------------
__global__ __launch_bounds__(256) void sortC_k(unsigned long long* __restrict__ keys)
{
    int t = blockIdx.x * 256 + threadIdx.x;      // over kB*8192
    int b = t >> 13, i = t & 8191;
    unsigned long long* p = keys + ((size_t)b << 14);
    unsigned long long a = p[i], c = p[i + 8192];
    if (a > c) { p[i] = c; p[i + 8192] = a; }
}

// ---------------------------------------------------------------------------
// Sort stage D: final merge strides 4096..1 within each 8192 half (all asc).
// ---------------------------------------------------------------------------
__global__ __launch_bounds__(512) void sortD_k(unsigned long long* __restrict__ keys)
{
    __shared__ unsigned long long lk[8192];
    unsigned long long* base = keys + ((size_t)blockIdx.x << 13);
    for (int t = threadIdx.x; t < 8192; t += 512) lk[t] = base[t];
    __syncthreads();
    for (int stride = 4096; stride > 0; stride >>= 1) {
#pragma unroll
        for (int p = 0; p < 8; ++p) {
            int n = threadIdx.x + (p << 9);
            int i = ((n & ~(stride - 1)) << 1) | (n & (stride - 1));
            int j = i + stride;
            unsigned long long a = lk[i], c = lk[j];
            if (a > c) { lk[i] = c; lk[j] = a; }
        }
        __syncthreads();
    }
    for (int t = threadIdx.x; t < 8192; t += 512) base[t] = lk[t];
}

// ---------------------------------------------------------------------------
// Stage 2: sorted greedy NMS traversal. One block per image, chunks of 256
// sorted candidates: parallel test vs kept list, then ballot-based in-chunk
// sequential resolve. Exactly equivalent to iterative argmax+suppress.
// ---------------------------------------------------------------------------
__global__ __launch_bounds__(256) void nms_k(
    const float4* __restrict__ boxes,
    const float* __restrict__ scores,
    const int* __restrict__ labels,
    const unsigned long long* __restrict__ keys,
    float* __restrict__ out)
{
    __shared__ float4 kbox[kMaxOut];
    __shared__ float karea[kMaxOut];
    __shared__ unsigned long long ball[4];
    __shared__ int firstt, kcS, doneS, stopS;

    const int b = blockIdx.x, tid = threadIdx.x;
    const unsigned long long* sk = keys + ((size_t)b << 14);
    const float4* bx = boxes + (size_t)b * kN;

    if (tid == 0) { kcS = 0; doneS = 0; }

    for (int c = 0; c < kNP / 256; ++c) {
        __syncthreads();                          // publish kc/kbox; guard stopS reuse
        if (tid == 0) stopS = (sk[c * 256] == ~0ULL);
        unsigned long long key = sk[c * 256 + tid];
        bool alive = (key != ~0ULL);
        int idx = alive ? (int)(key & 0xFFFFFFFFULL) : 0;
        float4 cb = bx[idx];
        float ac = (cb.z - cb.x) * (cb.w - cb.y);
        __syncthreads();
        if (stopS) break;                         // ascending sort: rest all invalid
        int kcl = kcS;
        if (alive) {
            for (int k = 0; k < kcl; ++k) {
                float4 kb = kbox[k];
                float t0 = fmaxf(kb.x, cb.x), t1 = fmaxf(kb.y, cb.y);
                float b0 = fminf(kb.z, cb.z), b1 = fminf(kb.w, cb.w);
                float inter = fmaxf(b0 - t0, 0.f) * fmaxf(b1 - t1, 0.f);
                float iou = inter / (karea[k] + ac - inter + 1e-9f);
                if (iou > kIouTh) { alive = false; break; }
            }
        }
        // in-chunk sequential resolve (rounds = keeps-in-chunk + 1)
        while (true) {
            unsigned long long m = __ballot((int)alive);
            if ((tid & 63) == 0) ball[tid >> 6] = m;
            __syncthreads();
            if (tid == 0) {
                int ft = -1;
                for (int w = 0; w < 4; ++w)
                    if (ball[w]) { ft = (w << 6) + __ffsll(ball[w]) - 1; break; }
                firstt = ft;
            }
            __syncthreads();
            int ft = firstt;
            if (ft < 0) break;
            if (tid == ft) {
                int k = kcS;
                kbox[k] = cb; karea[k] = ac;
                ((float4*)out)[b * kMaxOut + k] = cb;
                out[kB * kMaxOut * 4 + b * kMaxOut + k] =
                    (float)labels[(size_t)b * kN + idx];
                out[kB * kMaxOut * 5 + b * kMaxOut + k] =
                    scores[(size_t)b * kN + idx];
                kcS = k + 1;
                alive = false;
                if (k + 1 == kMaxOut) doneS = 1;
            }
            __syncthreads();
            if (doneS) break;
            int kn = kcS;                          // == old+1
            if (alive) {
                float4 kb = kbox[kn - 1];
                float t0 = fmaxf(kb.x, cb.x), t1 = fmaxf(kb.y, cb.y);
                float b0 = fminf(kb.z, cb.z), b1 = fminf(kb.w, cb.w);
                float inter = fmaxf(b0 - t0, 0.f) * fmaxf(b1 - t1, 0.f);
                float iou = inter / (karea[kn - 1] + ac - inter + 1e-9f);
                if (iou > kIouTh) alive = false;
            }
            __syncthreads();
        }
        if (doneS) break;
    }
    __syncthreads();
    int kcf = kcS;
    for (int k = kcf + tid; k < kMaxOut; k += 256) {
        ((float4*)out)[b * kMaxOut + k] = make_float4(0.f, 0.f, 0.f, 0.f);
        out[kB * kMaxOut * 4 + b * kMaxOut + k] = -1.0f;
        out[kB * kMaxOut * 5 + b * kMaxOut + k] = 0.0f;
    }
}

extern "C" void kernel_launch(void* const* d_in, const int* in_sizes, int n_in,
                              void* d_out, int out_size, void* d_ws, size_t ws_size,
                              hipStream_t stream)
{
    const float* preds = (const float*)d_in[0];
    const float* anchors = (const float*)d_in[1];
    float* out = (float*)d_out;

    char* ws = (char*)d_ws;
    float4* boxes = (float4*)ws;                                   // 8.60 MB
    float* scores = (float*)(ws + (size_t)kB * kN * 16);           // 2.15 MB
    int* labels = (int*)(ws + (size_t)kB * kN * 20);               // 2.15 MB
    unsigned long long* keys =
        (unsigned long long*)(ws + (size_t)kB * kN * 24);          // 8.39 MB (64*16384*8)

    int total = kB * kN;
    decode_k<<<(total + 255) / 256, 256, 0, stream>>>(preds, anchors, boxes, scores, labels);
    keys_k<<<(kB * kNP) / 256, 256, 0, stream>>>(scores, keys);
    sortB_k<<<kB * 2, 512, 0, stream>>>(keys);
    sortC_k<<<(kB * 8192) / 256, 256, 0, stream>>>(keys);
    sortD_k<<<kB * 2, 512, 0, stream>>>(keys);
    nms_k<<<kB, 256, 0, stream>>>(boxes, scores, labels, keys, out);
}

// Round 3
// 603.826 us; speedup vs baseline: 2.3690x; 1.0082x over previous
//
#include <hip/hip_runtime.h>

namespace {
constexpr int kB = 64;
constexpr int kN = 8400;
constexpr int kNP = 16384;          // padded pow2 per image for bitonic
constexpr int kReg = 64;
constexpr int kCls = 80;
constexpr int kStride = kReg + kCls; // 144
constexpr int kMaxOut = 100;
constexpr float kScoreTh = 0.3f;
constexpr float kIouTh = 0.5f;
}

// ---------------------------------------------------------------------------
// Stage 1 v2: coalesced decode. Block = 256 threads = 64 anchors x 4 sides.
// Stage 64x144 floats into LDS via coalesced float4 loads (padded rows of
// 148 floats), then 4 threads/anchor: DFL softmax per side + partial class
// argmax, combined with wave shuffles (lane order preserves tie-break).
// All float expressions bitwise-identical to the verified round-1 kernel.
// Also fuses NMS key packing (round-2 keys_k) into the epilogue.
// ---------------------------------------------------------------------------
__global__ __launch_bounds__(256) void decode2_k(
    const float* __restrict__ preds,
    const float* __restrict__ anchors,
    float4* __restrict__ boxes,
    float* __restrict__ scores,
    int* __restrict__ labels,
    unsigned long long* __restrict__ keys)
{
    __shared__ float lds[64 * 148];                 // 37.9 KB, rows padded 144->148
    const int tid = threadIdx.x;
    const size_t gbase = (size_t)blockIdx.x * 64;   // first anchor slot of block

    const float4* src = (const float4*)(preds + gbase * kStride);
    float4* l4 = (float4*)lds;
#pragma unroll
    for (int k = 0; k < 9; ++k) {                   // 2304 float4, coalesced
        int i = tid + k * 256;
        int row = i / 36, col = i - row * 36;
        l4[row * 37 + col] = src[i];
    }
    __syncthreads();

    const int a = tid >> 2, s = tid & 3;
    const float* rowp = lds + a * 148;

    // ---- DFL softmax-expectation for side s ----
    float x[16];
    const float4* q = (const float4*)(rowp + s * 16);
#pragma unroll
    for (int j = 0; j < 4; ++j) ((float4*)x)[j] = q[j];
    float m = x[0];
#pragma unroll
    for (int j = 1; j < 16; ++j) m = fmaxf(m, x[j]);
    float se = 0.f, we = 0.f;
#pragma unroll
    for (int j = 0; j < 16; ++j) {
        float t = expf(x[j] - m);
        se += t;
        we += t * (float)j;
    }
    float d = we / se;

    // ---- partial class argmax over [s*20, s*20+20) ----
    const float4* cl = (const float4*)(rowp + kReg + s * 20);
    float bv = -3e38f; int bi = 0;
#pragma unroll
    for (int c = 0; c < 5; ++c) {
        float4 v = cl[c];
        int cb = s * 20 + 4 * c;
        if (v.x > bv) { bv = v.x; bi = cb; }
        if (v.y > bv) { bv = v.y; bi = cb + 1; }
        if (v.z > bv) { bv = v.z; bi = cb + 2; }
        if (v.w > bv) { bv = v.w; bi = cb + 3; }
    }

    const int lane = tid & 63;
    const int base = lane & ~3;
    float d0 = __shfl(d, base + 0, 64);
    float d1 = __shfl(d, base + 1, 64);
    float d2 = __shfl(d, base + 2, 64);
    float d3 = __shfl(d, base + 3, 64);
    float v1 = __shfl(bv, base + 1, 64); int i1 = __shfl(bi, base + 1, 64);
    float v2 = __shfl(bv, base + 2, 64); int i2 = __shfl(bi, base + 2, 64);
    float v3 = __shfl(bv, base + 3, 64); int i3 = __shfl(bi, base + 3, 64);

    if (s == 0) {
        // ordered combine == full 0..79 scan with strict > (first occurrence)
        float best = bv; int bl = bi;
        if (v1 > best) { best = v1; bl = i1; }
        if (v2 > best) { best = v2; bl = i2; }
        if (v3 > best) { best = v3; bl = i3; }

        size_t gi = gbase + a;
        int bimg = (int)(gi / kN);
        int n = (int)(gi - (size_t)bimg * kN);
        float4 av = ((const float4*)anchors)[n];
        float ah0 = av.z - av.x, ah1 = av.w - av.y;
        float c0 = (av.x + av.z) * 0.5f, c1 = (av.y + av.w) * 0.5f;
        float bc0 = (d2 - d0) * 0.5f * ah0 + c0;
        float bc1 = (d3 - d1) * 0.5f * ah1 + c1;
        float bh0 = (d2 + d0) * ah0;
        float bh1 = (d3 + d1) * ah1;
        boxes[gi] = make_float4(bc0 - bh0 * 0.5f, bc1 - bh1 * 0.5f,
                                bc0 + bh0 * 0.5f, bc1 + bh1 * 0.5f);
        scores[gi] = best;
        labels[gi] = bl;

        unsigned long long kkey = ~0ULL;
        if (best > kScoreTh) {
            unsigned u = __float_as_uint(best);
            unsigned o = u ^ ((u & 0x80000000u) ? 0xFFFFFFFFu : 0x80000000u);
            kkey = ((unsigned long long)(~o) << 32) | (unsigned)n;
        }
        keys[((size_t)bimg << 14) + n] = kkey;
    }
}

// ---------------------------------------------------------------------------
// Sort stage B: bitonic stages size=2..8192 within each 8192-element half.
// Half h=0 ascending, h=1 descending -> 16384-elem bitonic sequence.
// Pad keys (n >= kN) are synthesized on load (decode2 only writes n < kN).
// ---------------------------------------------------------------------------
__global__ __launch_bounds__(512) void sortB_k(unsigned long long* __restrict__ keys)
{
    __shared__ unsigned long long lk[8192];      // 64 KB
    const int h = blockIdx.x & 1;
    unsigned long long* base = keys + ((size_t)blockIdx.x << 13);
    for (int t = threadIdx.x; t < 8192; t += 512)
        lk[t] = (h * 8192 + t < kN) ? base[t] : ~0ULL;
    __syncthreads();
    for (int size = 2; size <= 8192; size <<= 1) {
        const bool isTop = (size == 8192);
        for (int stride = size >> 1; stride > 0; stride >>= 1) {
#pragma unroll
            for (int p = 0; p < 8; ++p) {
                int n = threadIdx.x + (p << 9);
                int i = ((n & ~(stride - 1)) << 1) | (n & (stride - 1));
                int j = i + stride;
                bool desc = isTop ? (h == 1) : ((i & size) != 0);
                unsigned long long a = lk[i], c = lk[j];
                bool sw = desc ? (c > a) : (a > c);
                if (sw) { lk[i] = c; lk[j] = a; }
            }
            __syncthreads();
        }
    }
    for (int t = threadIdx.x; t < 8192; t += 512) base[t] = lk[t];
}

// ---------------------------------------------------------------------------
// Sort stage C: the single stride-8192 global pass of the final merge stage.
// ---------------------------------------------------------------------------
__global__ __launch_bounds__(256) void sortC_k(unsigned long long* __restrict__ keys)
{
    int t = blockIdx.x * 256 + threadIdx.x;      // over kB*8192
    int b = t >> 13, i = t & 8191;
    unsigned long long* p = keys + ((size_t)b << 14);
    unsigned long long a = p[i], c = p[i + 8192];
    if (a > c) { p[i] = c; p[i + 8192] = a; }
}

// ---------------------------------------------------------------------------
// Sort stage D: final merge strides 4096..1 within each 8192 half (all asc).
// ---------------------------------------------------------------------------
__global__ __launch_bounds__(512) void sortD_k(unsigned long long* __restrict__ keys)
{
    __shared__ unsigned long long lk[8192];
    unsigned long long* base = keys + ((size_t)blockIdx.x << 13);
    for (int t = threadIdx.x; t < 8192; t += 512) lk[t] = base[t];
    __syncthreads();
    for (int stride = 4096; stride > 0; stride >>= 1) {
#pragma unroll
        for (int p = 0; p < 8; ++p) {
            int n = threadIdx.x + (p << 9);
            int i = ((n & ~(stride - 1)) << 1) | (n & (stride - 1));
            int j = i + stride;
            unsigned long long a = lk[i], c = lk[j];
            if (a > c) { lk[i] = c; lk[j] = a; }
        }
        __syncthreads();
    }
    for (int t = threadIdx.x; t < 8192; t += 512) base[t] = lk[t];
}

// ---------------------------------------------------------------------------
// Stage 2: sorted greedy NMS traversal (unchanged from round 2, absmax 0.0).
// ---------------------------------------------------------------------------
__global__ __launch_bounds__(256) void nms_k(
    const float4* __restrict__ boxes,
    const float* __restrict__ scores,
    const int* __restrict__ labels,
    const unsigned long long* __restrict__ keys,
    float* __restrict__ out)
{
    __shared__ float4 kbox[kMaxOut];
    __shared__ float karea[kMaxOut];
    __shared__ unsigned long long ball[4];
    __shared__ int firstt, kcS, doneS, stopS;

    const int b = blockIdx.x, tid = threadIdx.x;
    const unsigned long long* sk = keys + ((size_t)b << 14);
    const float4* bx = boxes + (size_t)b * kN;

    if (tid == 0) { kcS = 0; doneS = 0; }

    for (int c = 0; c < kNP / 256; ++c) {
        __syncthreads();
        if (tid == 0) stopS = (sk[c * 256] == ~0ULL);
        unsigned long long key = sk[c * 256 + tid];
        bool alive = (key != ~0ULL);
        int idx = alive ? (int)(key & 0xFFFFFFFFULL) : 0;
        float4 cb = bx[idx];
        float ac = (cb.z - cb.x) * (cb.w - cb.y);
        __syncthreads();
        if (stopS) break;
        int kcl = kcS;
        if (alive) {
            for (int k = 0; k < kcl; ++k) {
                float4 kb = kbox[k];
                float t0 = fmaxf(kb.x, cb.x), t1 = fmaxf(kb.y, cb.y);
                float b0 = fminf(kb.z, cb.z), b1 = fminf(kb.w, cb.w);
                float inter = fmaxf(b0 - t0, 0.f) * fmaxf(b1 - t1, 0.f);
                float iou = inter / (karea[k] + ac - inter + 1e-9f);
                if (iou > kIouTh) { alive = false; break; }
            }
        }
        while (true) {
            unsigned long long mm = __ballot((int)alive);
            if ((tid & 63) == 0) ball[tid >> 6] = mm;
            __syncthreads();
            if (tid == 0) {
                int ft = -1;
                for (int w = 0; w < 4; ++w)
                    if (ball[w]) { ft = (w << 6) + __ffsll(ball[w]) - 1; break; }
                firstt = ft;
            }
            __syncthreads();
            int ft = firstt;
            if (ft < 0) break;
            if (tid == ft) {
                int k = kcS;
                kbox[k] = cb; karea[k] = ac;
                ((float4*)out)[b * kMaxOut + k] = cb;
                out[kB * kMaxOut * 4 + b * kMaxOut + k] =
                    (float)labels[(size_t)b * kN + idx];
                out[kB * kMaxOut * 5 + b * kMaxOut + k] =
                    scores[(size_t)b * kN + idx];
                kcS = k + 1;
                alive = false;
                if (k + 1 == kMaxOut) doneS = 1;
            }
            __syncthreads();
            if (doneS) break;
            int kn = kcS;
            if (alive) {
                float4 kb = kbox[kn - 1];
                float t0 = fmaxf(kb.x, cb.x), t1 = fmaxf(kb.y, cb.y);
                float b0 = fminf(kb.z, cb.z), b1 = fminf(kb.w, cb.w);
                float inter = fmaxf(b0 - t0, 0.f) * fmaxf(b1 - t1, 0.f);
                float iou = inter / (karea[kn - 1] + ac - inter + 1e-9f);
                if (iou > kIouTh) alive = false;
            }
            __syncthreads();
        }
        if (doneS) break;
    }
    __syncthreads();
    int kcf = kcS;
    for (int k = kcf + tid; k < kMaxOut; k += 256) {
        ((float4*)out)[b * kMaxOut + k] = make_float4(0.f, 0.f, 0.f, 0.f);
        out[kB * kMaxOut * 4 + b * kMaxOut + k] = -1.0f;
        out[kB * kMaxOut * 5 + b * kMaxOut + k] = 0.0f;
    }
}

extern "C" void kernel_launch(void* const* d_in, const int* in_sizes, int n_in,
                              void* d_out, int out_size, void* d_ws, size_t ws_size,
                              hipStream_t stream)
{
    const float* preds = (const float*)d_in[0];
    const float* anchors = (const float*)d_in[1];
    float* out = (float*)d_out;

    char* ws = (char*)d_ws;
    float4* boxes = (float4*)ws;                                   // 8.60 MB
    float* scores = (float*)(ws + (size_t)kB * kN * 16);           // 2.15 MB
    int* labels = (int*)(ws + (size_t)kB * kN * 20);               // 2.15 MB
    unsigned long long* keys =
        (unsigned long long*)(ws + (size_t)kB * kN * 24);          // 8.39 MB (64*16384*8)

    decode2_k<<<(kB * kN) / 64, 256, 0, stream>>>(preds, anchors, boxes, scores, labels, keys);
    sortB_k<<<kB * 2, 512, 0, stream>>>(keys);
    sortC_k<<<(kB * 8192) / 256, 256, 0, stream>>>(keys);
    sortD_k<<<kB * 2, 512, 0, stream>>>(keys);
    nms_k<<<kB, 256, 0, stream>>>(boxes, scores, labels, keys, out);
}

// Round 4
// 559.041 us; speedup vs baseline: 2.5588x; 1.0801x over previous
//
#include <hip/hip_runtime.h>

namespace {
constexpr int kB = 64;
constexpr int kN = 8400;
constexpr int kMain = 8192;          // bitonic-sorted main segment per image
constexpr int kTail = kN - kMain;    // 208, sorted in-LDS inside nms
constexpr int kReg = 64;
constexpr int kCls = 80;
constexpr int kStride = kReg + kCls; // 144
constexpr int kMaxOut = 100;
constexpr float kScoreTh = 0.3f;
constexpr float kIouTh = 0.5f;
}

// ---------------------------------------------------------------------------
// Stage 1: coalesced decode (verified absmax 0.0 in round 3). Block = 256
// threads = 64 anchors x 4 sides; LDS staging; fused NMS key packing.
// ---------------------------------------------------------------------------
__global__ __launch_bounds__(256) void decode2_k(
    const float* __restrict__ preds,
    const float* __restrict__ anchors,
    float4* __restrict__ boxes,
    float* __restrict__ scores,
    int* __restrict__ labels,
    unsigned long long* __restrict__ keys)
{
    __shared__ float lds[64 * 148];
    const int tid = threadIdx.x;
    const size_t gbase = (size_t)blockIdx.x * 64;

    const float4* src = (const float4*)(preds + gbase * kStride);
    float4* l4 = (float4*)lds;
#pragma unroll
    for (int k = 0; k < 9; ++k) {
        int i = tid + k * 256;
        int row = i / 36, col = i - row * 36;
        l4[row * 37 + col] = src[i];
    }
    __syncthreads();

    const int a = tid >> 2, s = tid & 3;
    const float* rowp = lds + a * 148;

    float x[16];
    const float4* q = (const float4*)(rowp + s * 16);
#pragma unroll
    for (int j = 0; j < 4; ++j) ((float4*)x)[j] = q[j];
    float m = x[0];
#pragma unroll
    for (int j = 1; j < 16; ++j) m = fmaxf(m, x[j]);
    float se = 0.f, we = 0.f;
#pragma unroll
    for (int j = 0; j < 16; ++j) {
        float t = expf(x[j] - m);
        se += t;
        we += t * (float)j;
    }
    float d = we / se;

    const float4* cl = (const float4*)(rowp + kReg + s * 20);
    float bv = -3e38f; int bi = 0;
#pragma unroll
    for (int c = 0; c < 5; ++c) {
        float4 v = cl[c];
        int cb = s * 20 + 4 * c;
        if (v.x > bv) { bv = v.x; bi = cb; }
        if (v.y > bv) { bv = v.y; bi = cb + 1; }
        if (v.z > bv) { bv = v.z; bi = cb + 2; }
        if (v.w > bv) { bv = v.w; bi = cb + 3; }
    }

    const int lane = tid & 63;
    const int base = lane & ~3;
    float d0 = __shfl(d, base + 0, 64);
    float d1 = __shfl(d, base + 1, 64);
    float d2 = __shfl(d, base + 2, 64);
    float d3 = __shfl(d, base + 3, 64);
    float v1 = __shfl(bv, base + 1, 64); int i1 = __shfl(bi, base + 1, 64);
    float v2 = __shfl(bv, base + 2, 64); int i2 = __shfl(bi, base + 2, 64);
    float v3 = __shfl(bv, base + 3, 64); int i3 = __shfl(bi, base + 3, 64);

    if (s == 0) {
        float best = bv; int bl = bi;
        if (v1 > best) { best = v1; bl = i1; }
        if (v2 > best) { best = v2; bl = i2; }
        if (v3 > best) { best = v3; bl = i3; }

        size_t gi = gbase + a;
        int bimg = (int)(gi / kN);
        int n = (int)(gi - (size_t)bimg * kN);
        float4 av = ((const float4*)anchors)[n];
        float ah0 = av.z - av.x, ah1 = av.w - av.y;
        float c0 = (av.x + av.z) * 0.5f, c1 = (av.y + av.w) * 0.5f;
        float bc0 = (d2 - d0) * 0.5f * ah0 + c0;
        float bc1 = (d3 - d1) * 0.5f * ah1 + c1;
        float bh0 = (d2 + d0) * ah0;
        float bh1 = (d3 + d1) * ah1;
        boxes[gi] = make_float4(bc0 - bh0 * 0.5f, bc1 - bh1 * 0.5f,
                                bc0 + bh0 * 0.5f, bc1 + bh1 * 0.5f);
        scores[gi] = best;
        labels[gi] = bl;

        unsigned long long kkey = ~0ULL;
        if (best > kScoreTh) {
            unsigned u = __float_as_uint(best);
            unsigned o = u ^ ((u & 0x80000000u) ? 0xFFFFFFFFu : 0x80000000u);
            kkey = ((unsigned long long)(~o) << 32) | (unsigned)n;
        }
        keys[((size_t)bimg << 14) + n] = kkey;
    }
}

// ---------------------------------------------------------------------------
// Sort: full ascending bitonic of the 8192-key main segment. One block per
// image. (i & size) comparator direction makes the final stage ascending
// automatically (i < 8192 == size).
// ---------------------------------------------------------------------------
__global__ __launch_bounds__(512) void sortB_k(unsigned long long* __restrict__ keys)
{
    __shared__ unsigned long long lk[8192];      // 64 KB
    unsigned long long* base = keys + ((size_t)blockIdx.x << 14);
    for (int t = threadIdx.x; t < 8192; t += 512) lk[t] = base[t];
    __syncthreads();
    for (int size = 2; size <= 8192; size <<= 1) {
        for (int stride = size >> 1; stride > 0; stride >>= 1) {
#pragma unroll
            for (int p = 0; p < 8; ++p) {
                int n = threadIdx.x + (p << 9);
                int i = ((n & ~(stride - 1)) << 1) | (n & (stride - 1));
                int j = i + stride;
                bool desc = (i & size) != 0;
                unsigned long long a = lk[i], c = lk[j];
                bool sw = desc ? (c > a) : (a > c);
                if (sw) { lk[i] = c; lk[j] = a; }
            }
            __syncthreads();
        }
    }
    for (int t = threadIdx.x; t < 8192; t += 512) base[t] = lk[t];
}

// ---------------------------------------------------------------------------
// Stage 2: sorted greedy NMS with on-the-fly 2-way merge (main 8192 asc via
// merge-path, tail 208 sorted in LDS) and wave0-only in-chunk resolve.
// Exact order equivalence: keys unique; pads ~0ULL; A-first tie rule matches
// idx ordering (A idx < 8192 <= B idx).
// ---------------------------------------------------------------------------
__device__ __forceinline__ unsigned long long getB_(
    const unsigned long long* tailL, int p1, int x)
{
    int t = p1 + x;
    return (t < 256) ? tailL[t] : ~0ULL;
}

__global__ __launch_bounds__(256) void nms_k(
    const float4* __restrict__ boxes,
    const float* __restrict__ scores,
    const int* __restrict__ labels,
    const unsigned long long* __restrict__ keys,
    float* __restrict__ out)
{
    __shared__ unsigned long long tailL[256];
    __shared__ unsigned long long aw[512];
    __shared__ float4 sbox[256];
    __shared__ float  sar[256];
    __shared__ int    sidx[256];
    __shared__ float4 kboxL[kMaxOut];
    __shared__ float  kareaL[kMaxOut];
    __shared__ int    kidxL[kMaxOut];
    __shared__ unsigned long long ballS[4];
    __shared__ int p0S, p1S, kcS, doneS, stopS;

    const int b = blockIdx.x, tid = threadIdx.x;
    const unsigned long long* mainA = keys + ((size_t)b << 14);
    const float4* bx = boxes + (size_t)b * kN;

    if (tid == 0) { p0S = 0; p1S = 0; kcS = 0; doneS = 0; }

    // ---- sort the 208-key tail (pad to 256) in LDS, ascending bitonic ----
    tailL[tid] = (tid < kTail) ? mainA[kMain + tid] : ~0ULL;
    __syncthreads();
    for (int size = 2; size <= 256; size <<= 1) {
        for (int stride = size >> 1; stride > 0; stride >>= 1) {
            if (tid < 128) {
                int i = ((tid & ~(stride - 1)) << 1) | (tid & (stride - 1));
                int j = i + stride;
                bool desc = (i & size) != 0;
                unsigned long long a = tailL[i], c = tailL[j];
                bool sw = desc ? (c > a) : (a > c);
                if (sw) { tailL[i] = c; tailL[j] = a; }
            }
            __syncthreads();
        }
    }

    int kc = 0;
    for (int c = 0; c < 33; ++c) {
        int p0 = p0S, p1 = p1S;          // synced by previous barrier
        aw[tid]       = (p0 + tid       < kMain) ? mainA[p0 + tid]       : ~0ULL;
        aw[tid + 256] = (p0 + tid + 256 < kMain) ? mainA[p0 + tid + 256] : ~0ULL;
        __syncthreads();                  // B1: window visible

        // ---- merge-path: thread t produces merged element at diagonal t ----
        int d = tid;
        int lo = 0, hi = d;
        while (lo < hi) {
            int mid = (lo + hi) >> 1;     // mid < d
            bool c2 = getB_(tailL, p1, d - mid - 1) < aw[mid];
            if (c2) hi = mid; else lo = mid + 1;
        }
        unsigned long long av = aw[lo];
        unsigned long long bv = getB_(tailL, p1, d - lo);
        unsigned long long key = (av <= bv) ? av : bv;   // A-first ties (pads only)

        bool alive = (key != ~0ULL);
        int idx = alive ? (int)(key & 0xFFFFFFFFULL) : 0;
        float4 cb = bx[idx];
        float ac = (cb.z - cb.x) * (cb.w - cb.y);

        // ---- pre-test vs keeps from previous chunks ----
        if (alive) {
            for (int k = 0; k < kc; ++k) {
                float4 kb = kboxL[k];
                float t0 = fmaxf(kb.x, cb.x), t1 = fmaxf(kb.y, cb.y);
                float b0 = fminf(kb.z, cb.z), b1 = fminf(kb.w, cb.w);
                float inter = fmaxf(b0 - t0, 0.f) * fmaxf(b1 - t1, 0.f);
                float iou = inter / (kareaL[k] + ac - inter + 1e-9f);
                if (iou > kIouTh) { alive = false; break; }
            }
        }
        sbox[tid] = cb; sar[tid] = ac; sidx[tid] = idx;
        unsigned long long mm = __ballot((int)alive);
        if ((tid & 63) == 0) ballS[tid >> 6] = mm;
        if (tid == 0) {
            stopS = (key == ~0ULL);       // diagonal-0 key == min remaining
            // advance pointers: merge-path at diagonal 256
            int lo2 = 0, hi2 = 256;
            while (lo2 < hi2) {
                int mid = (lo2 + hi2) >> 1;
                bool c2 = getB_(tailL, p1, 255 - mid) < aw[mid];
                if (c2) hi2 = mid; else lo2 = mid + 1;
            }
            p0S = p0 + lo2; p1S = p1 + (256 - lo2);
        }
        __syncthreads();                  // B2: sbox/ball/stop/pointers visible
        if (stopS) break;

        // ---- wave0-only in-chunk greedy resolve (no block barriers) ----
        if (tid < 64) {
            const int lane = tid;
            unsigned a4 = 0;
#pragma unroll
            for (int j = 0; j < 4; ++j)
                a4 |= (unsigned)((ballS[j] >> lane) & 1ULL) << j;
            int kcl = kc;
            while (true) {
                int jF = -1, lF = 0;
#pragma unroll
                for (int j = 0; j < 4; ++j) {
                    if (jF < 0) {
                        unsigned long long m2 = __ballot((int)((a4 >> j) & 1u));
                        if (m2) { jF = j; lF = __ffsll((unsigned long long)m2) - 1; }
                    }
                }
                if (jF < 0) break;
                int cs = (jF << 6) + lF;
                float4 kb = sbox[cs];
                float kar = sar[cs];
                if (lane == 0) {
                    kboxL[kcl] = kb; kareaL[kcl] = kar; kidxL[kcl] = sidx[cs];
                }
                if (lane == lF) a4 &= ~(1u << jF);
                ++kcl;
                if (kcl == kMaxOut) break;
#pragma unroll
                for (int j = 0; j < 4; ++j) {
                    if ((a4 >> j) & 1u) {
                        float4 cb2 = sbox[lane + (j << 6)];
                        float ac2 = sar[lane + (j << 6)];
                        float t0 = fmaxf(kb.x, cb2.x), t1 = fmaxf(kb.y, cb2.y);
                        float b0 = fminf(kb.z, cb2.z), b1 = fminf(kb.w, cb2.w);
                        float inter = fmaxf(b0 - t0, 0.f) * fmaxf(b1 - t1, 0.f);
                        float iou = inter / (kar + ac2 - inter + 1e-9f);
                        if (iou > kIouTh) a4 &= ~(1u << j);
                    }
                }
            }
            if (lane == 0) { kcS = kcl; if (kcl == kMaxOut) doneS = 1; }
        }
        __syncthreads();                  // B3: keeps visible
        kc = kcS;
        if (doneS) break;
    }

    // ---- epilogue: parallel output ----
    int kcf = kcS;
    if (tid < kMaxOut) {
        if (tid < kcf) {
            int idx = kidxL[tid];
            ((float4*)out)[b * kMaxOut + tid] = kboxL[tid];
            out[kB * kMaxOut * 4 + b * kMaxOut + tid] =
                (float)labels[(size_t)b * kN + idx];
            out[kB * kMaxOut * 5 + b * kMaxOut + tid] =
                scores[(size_t)b * kN + idx];
        } else {
            ((float4*)out)[b * kMaxOut + tid] = make_float4(0.f, 0.f, 0.f, 0.f);
            out[kB * kMaxOut * 4 + b * kMaxOut + tid] = -1.0f;
            out[kB * kMaxOut * 5 + b * kMaxOut + tid] = 0.0f;
        }
    }
}

extern "C" void kernel_launch(void* const* d_in, const int* in_sizes, int n_in,
                              void* d_out, int out_size, void* d_ws, size_t ws_size,
                              hipStream_t stream)
{
    const float* preds = (const float*)d_in[0];
    const float* anchors = (const float*)d_in[1];
    float* out = (float*)d_out;

    char* ws = (char*)d_ws;
    float4* boxes = (float4*)ws;                                   // 8.60 MB
    float* scores = (float*)(ws + (size_t)kB * kN * 16);           // 2.15 MB
    int* labels = (int*)(ws + (size_t)kB * kN * 20);               // 2.15 MB
    unsigned long long* keys =
        (unsigned long long*)(ws + (size_t)kB * kN * 24);          // 64*16384*8

    decode2_k<<<(kB * kN) / 64, 256, 0, stream>>>(preds, anchors, boxes, scores, labels, keys);
    sortB_k<<<kB, 512, 0, stream>>>(keys);
    nms_k<<<kB, 256, 0, stream>>>(boxes, scores, labels, keys, out);
}